// Round 1
// 497.652 us; speedup vs baseline: 1.1489x; 1.1489x over previous
//
#include <hip/hip_runtime.h>
#include <hip/hip_fp16.h>

// FeatureGrid: trilinear interp of N points into (C=32, 128^3) f32 grid.
// v2: fp16 (S,C) workspace. One corner row = 32ch * 2B = 64B = one cache
// line, and the whole workspace (128 MiB) fits the 256 MiB Infinity Cache
// with room for the output write stream -> gather becomes L3-resident.

constexpr int   GD      = 128;                         // grid dim per axis
constexpr long long SPATIAL = (long long)GD * GD * GD; // 2097152
constexpr int   FD      = 32;                          // channels
constexpr float PLO     = -10.0f;
constexpr float PHI     = 10.0f;

typedef float nfloat4 __attribute__((ext_vector_type(4)));

// ---------------- transpose+convert (C,S) f32 -> (S,C) fp16 ----------------
// tile: 32 channels x 64 spatial per block; 256 threads.
// reads: wave = 64 lanes read 64 consecutive s for one c (256 B contig),
//        nontemporal (stream-once; keep L3 for the fp16 workspace).
// writes: wave writes 4 points x 32ch fp16 = 256 B contig.
// LDS stride 33 -> max 2-way bank aliasing (free on gfx950).
__global__ __launch_bounds__(256) void transpose_feat_h(
    const float* __restrict__ f, __half* __restrict__ o) {
    __shared__ float lds[64][FD + 1];
    const int t  = threadIdx.x;
    const long long s0 = (long long)blockIdx.x * 64;
    const int sl = t & 63;   // spatial within tile
    const int cq = t >> 6;   // 0..3
#pragma unroll
    for (int it = 0; it < 8; ++it) {
        const int c = it * 4 + cq;
        lds[sl][c] =
            __builtin_nontemporal_load(f + (size_t)c * SPATIAL + s0 + sl);
    }
    __syncthreads();
    const int c0 = (t & 15) * 2;  // channel pair
    const int sw = t >> 4;        // 0..15
#pragma unroll
    for (int it = 0; it < 4; ++it) {
        const int s = sw + it * 16;
        __half2 h;
        h.x = __float2half(lds[s][c0]);
        h.y = __float2half(lds[s][c0 + 1]);
        *reinterpret_cast<__half2*>(o + (size_t)(s0 + s) * FD + c0) = h;
    }
}

// ---------------- gather: 4 threads per point, fp16 feature ----------------
// each thread owns 8 channels: one 16-B load per corner (4 thr * 16 B = the
// full 64-B corner line), fp16->f32 convert, fma, 32-B f32 output store.
__global__ __launch_bounds__(256) void trilerp_h(
    const float* __restrict__ x, const __half* __restrict__ ft,
    float* __restrict__ out, int npts) {
    const int tid = blockIdx.x * 256 + threadIdx.x;
    const int n = tid >> 2;
    if (n >= npts) return;
    const int j = tid & 3;  // channel octet

    const float px = x[3 * n + 0];
    const float py = x[3 * n + 1];
    const float pz = x[3 * n + 2];

    // match reference arithmetic order
    const float cx = 2.0f * (px - PLO) / (PHI - PLO) - 1.0f;
    const float cy = 2.0f * (py - PLO) / (PHI - PLO) - 1.0f;
    const float cz = 2.0f * (pz - PLO) / (PHI - PLO) - 1.0f;
    const float fx = ((cx + 1.0f) * GD - 1.0f) * 0.5f;
    const float fy = ((cy + 1.0f) * GD - 1.0f) * 0.5f;
    const float fz = ((cz + 1.0f) * GD - 1.0f) * 0.5f;

    const float x0f = floorf(fx), y0f = floorf(fy), z0f = floorf(fz);
    const float wx = fx - x0f, wy = fy - y0f, wz = fz - z0f;
    const int x0 = (int)x0f, y0 = (int)y0f, z0 = (int)z0f;

    float acc[8] = {0.f, 0.f, 0.f, 0.f, 0.f, 0.f, 0.f, 0.f};
#pragma unroll
    for (int dz = 0; dz < 2; ++dz) {
#pragma unroll
        for (int dy = 0; dy < 2; ++dy) {
#pragma unroll
            for (int dx = 0; dx < 2; ++dx) {
                const int xi = x0 + dx, yi = y0 + dy, zi = z0 + dz;
                const bool valid = ((unsigned)xi < (unsigned)GD) &
                                   ((unsigned)yi < (unsigned)GD) &
                                   ((unsigned)zi < (unsigned)GD);
                float w = (dx ? wx : 1.0f - wx) * (dy ? wy : 1.0f - wy) *
                          (dz ? wz : 1.0f - wz);
                w = valid ? w : 0.0f;
                const int xc = min(max(xi, 0), GD - 1);
                const int yc = min(max(yi, 0), GD - 1);
                const int zc = min(max(zi, 0), GD - 1);
                const size_t idx = (size_t)(zc * GD + yc) * GD + xc;
                const nfloat4 raw = *reinterpret_cast<const nfloat4*>(
                    ft + idx * FD + j * 8);
                const __half2* h2 = reinterpret_cast<const __half2*>(&raw);
#pragma unroll
                for (int k = 0; k < 4; ++k) {
                    const float2 fv = __half22float2(h2[k]);
                    acc[2 * k + 0] = fmaf(fv.x, w, acc[2 * k + 0]);
                    acc[2 * k + 1] = fmaf(fv.y, w, acc[2 * k + 1]);
                }
            }
        }
    }
    float* op = out + (size_t)n * FD + j * 8;
    nfloat4 o0 = {acc[0], acc[1], acc[2], acc[3]};
    nfloat4 o1 = {acc[4], acc[5], acc[6], acc[7]};
    // write-once stream: bypass-hint so it doesn't evict the fp16 workspace
    __builtin_nontemporal_store(o0, reinterpret_cast<nfloat4*>(op));
    __builtin_nontemporal_store(o1, reinterpret_cast<nfloat4*>(op) + 1);
}

// ---------------- fallback: direct gather in (C,S) layout ----------------
__global__ __launch_bounds__(256) void trilerp_direct(
    const float* __restrict__ x, const float* __restrict__ f,
    float* __restrict__ out, int npts) {
    const int tid = blockIdx.x * 256 + threadIdx.x;
    const int n = tid >> 3;
    if (n >= npts) return;
    const int j = tid & 7;

    const float px = x[3 * n + 0];
    const float py = x[3 * n + 1];
    const float pz = x[3 * n + 2];
    const float cx = 2.0f * (px - PLO) / (PHI - PLO) - 1.0f;
    const float cy = 2.0f * (py - PLO) / (PHI - PLO) - 1.0f;
    const float cz = 2.0f * (pz - PLO) / (PHI - PLO) - 1.0f;
    const float fx = ((cx + 1.0f) * GD - 1.0f) * 0.5f;
    const float fy = ((cy + 1.0f) * GD - 1.0f) * 0.5f;
    const float fz = ((cz + 1.0f) * GD - 1.0f) * 0.5f;
    const float x0f = floorf(fx), y0f = floorf(fy), z0f = floorf(fz);
    const float wx = fx - x0f, wy = fy - y0f, wz = fz - z0f;
    const int x0 = (int)x0f, y0 = (int)y0f, z0 = (int)z0f;

    float acc[4] = {0.f, 0.f, 0.f, 0.f};
#pragma unroll
    for (int dz = 0; dz < 2; ++dz)
#pragma unroll
        for (int dy = 0; dy < 2; ++dy)
#pragma unroll
            for (int dx = 0; dx < 2; ++dx) {
                const int xi = x0 + dx, yi = y0 + dy, zi = z0 + dz;
                const bool valid = ((unsigned)xi < (unsigned)GD) &
                                   ((unsigned)yi < (unsigned)GD) &
                                   ((unsigned)zi < (unsigned)GD);
                float w = (dx ? wx : 1.0f - wx) * (dy ? wy : 1.0f - wy) *
                          (dz ? wz : 1.0f - wz);
                w = valid ? w : 0.0f;
                const int xc = min(max(xi, 0), GD - 1);
                const int yc = min(max(yi, 0), GD - 1);
                const int zc = min(max(zi, 0), GD - 1);
                const size_t idx = (size_t)(zc * GD + yc) * GD + xc;
#pragma unroll
                for (int k = 0; k < 4; ++k)
                    acc[k] = fmaf(f[(size_t)(j * 4 + k) * SPATIAL + idx], w, acc[k]);
            }
#pragma unroll
    for (int k = 0; k < 4; ++k) out[(size_t)n * FD + j * 4 + k] = acc[k];
}

extern "C" void kernel_launch(void* const* d_in, const int* in_sizes, int n_in,
                              void* d_out, int out_size, void* d_ws, size_t ws_size,
                              hipStream_t stream) {
    const float* x    = (const float*)d_in[0];
    const float* feat = (const float*)d_in[1];
    float*       out  = (float*)d_out;
    const int npts = in_sizes[0] / 3;

    const size_t need = (size_t)SPATIAL * FD * sizeof(__half);  // 128 MiB

    if (ws_size >= need) {
        __half* fth = (__half*)d_ws;
        transpose_feat_h<<<(int)(SPATIAL / 64), 256, 0, stream>>>(feat, fth);
        const int gblocks = (npts * 4 + 255) / 256;
        trilerp_h<<<gblocks, 256, 0, stream>>>(x, fth, out, npts);
    } else {
        const int gblocks = (npts * 8 + 255) / 256;
        trilerp_direct<<<gblocks, 256, 0, stream>>>(x, feat, out, npts);
    }
}